// Round 10
// baseline (501.788 us; speedup 1.0000x reference)
//
#include <hip/hip_runtime.h>
#include <math.h>

#define NHEADS 16
#define HDIM   64
#define HID    1024
#define BATCH  2
#define SEQ    2048
#define NX (BATCH*SEQ*HID)       // 4194304
#define NW (HID*HID)             // 1048576

typedef unsigned short u16;
typedef __attribute__((ext_vector_type(8))) short  bf16x8;   // 8 bf16 = 4 VGPR
typedef __attribute__((ext_vector_type(8))) unsigned short u16x8;
typedef __attribute__((ext_vector_type(4))) float  f32x4;

// ---------------------------------------------------------------------------
// Fragment-tiled layout ("FT"): operand rows r, inner dim k. Subtile =
// 16 rows x 32 k. Element (r,k) lives at
//   ((r>>4)*KB + (k>>5))*512 + ((k>>3)&3)*128 + (r&15)*8 + (k&7)     [u16]
// (KB = k-blocks per row-block row). A wave's MFMA fragment load
// (lane = quad*16+lx -> 16B) is then 64 lanes x 16B CONTIGUOUS.
// hi / lo planes are separate arrays (keeps lane stride 16B).
// ---------------------------------------------------------------------------

// v_perm-based split: hi pair = bytes[2,3] of each fp32 (truncated bf16),
// lo pair = bytes[2,3] of (p - hi) — numerically identical to shift form.
__device__ __forceinline__ void split8(const float* xf, bf16x8& hi, bf16x8& lo) {
    unsigned* hp = (unsigned*)&hi;
    unsigned* lp = (unsigned*)&lo;
#pragma unroll
    for (int j = 0; j < 4; j++) {
        const float p0 = xf[2 * j], p1 = xf[2 * j + 1];
        const unsigned u0 = __float_as_uint(p0);
        const unsigned u1 = __float_as_uint(p1);
        hp[j] = __builtin_amdgcn_perm(u1, u0, 0x07060302u);
        const float l0 = p0 - __uint_as_float(u0 & 0xFFFF0000u);
        const float l1 = p1 - __uint_as_float(u1 & 0xFFFF0000u);
        lp[j] = __builtin_amdgcn_perm(__float_as_uint(l1), __float_as_uint(l0), 0x07060302u);
    }
}
__device__ __forceinline__ void split1(float v, u16& h, u16& l) {
    unsigned u = __float_as_uint(v);
    h = (u16)(u >> 16);
    l = (u16)(__float_as_uint(v - __uint_as_float(u & 0xFFFF0000u)) >> 16);
}

// ---------------------------------------------------------------------------
// RoPE tables
// ---------------------------------------------------------------------------
__global__ void rope_tables_kernel(float* __restrict__ ct, float* __restrict__ st) {
    int idx = blockIdx.x * 256 + threadIdx.x;
    if (idx >= SEQ * HDIM) return;
    int s  = idx >> 6;
    int dh = idx & 63;
    int i  = dh & 31;
    float inv = exp2f(-(float)i * (13.28771237954945f / 32.0f));  // log2(10000)/32
    float fr  = (float)s * inv;
    ct[idx] = cosf(fr);
    st[idx] = sinf(fr);
}

// ---------------------------------------------------------------------------
// Pre-pass v2 (unchanged from round 9): one wave per 512-u16 subtile,
// coalesced 1KB wave-stores.
// ---------------------------------------------------------------------------
__global__ __launch_bounds__(256) void split_kernel(
    const float* __restrict__ X,
    const float* __restrict__ W0,
    const float* __restrict__ W1,
    const float* __restrict__ W2,
    u16* __restrict__ Xhi, u16* __restrict__ Xlo,
    u16* __restrict__ Whi, u16* __restrict__ Wlo)
{
    const int s = blockIdx.x * 4 + (threadIdx.x >> 6);
    const int l = threadIdx.x & 63;
    const int r = l & 15, q = l >> 4;
    const float* src; u16* dh; u16* dl; int so;
    if (s < 8192) { src = X; dh = Xhi; dl = Xlo; so = s; }
    else {
        const int wi = (s - 8192) >> 11;
        so = (s - 8192) & 2047;
        src = (wi == 0) ? W0 : ((wi == 1) ? W1 : W2);
        dh = Whi + (size_t)wi * NW;
        dl = Wlo + (size_t)wi * NW;
    }
    const int R0 = (so >> 5) << 4, K0 = (so & 31) << 5;
    const float* sp = src + (size_t)(R0 + r) * 1024 + K0 + q * 8;
    float v[8];
    *(float4*)&v[0] = *(const float4*)sp;
    *(float4*)&v[4] = *(const float4*)(sp + 4);
    u16x8 h8, l8;
#pragma unroll
    for (int e = 0; e < 8; e++) {
        u16 hh, ll;
        split1(v[e], hh, ll);
        h8[e] = hh; l8[e] = ll;
    }
    const size_t off = (size_t)so * 512 + l * 8;
    *(u16x8*)(dh + off) = h8;
    *(u16x8*)(dl + off) = l8;
}

// ---------------------------------------------------------------------------
// MFMA QKV GEMM (unchanged from round 6): no LDS in K-loop, frag-tiled
// global fragments, XCD n-ownership remap, 2x-unrolled role-swapped
// register double-buffer, s_setprio around MFMA clusters.
// ---------------------------------------------------------------------------
__global__ __launch_bounds__(256, 2) void qkv_mfma_kernel(
    const u16* __restrict__ Xhi, const u16* __restrict__ Xlo,
    const u16* __restrict__ Whi, const u16* __restrict__ Wlo,
    const float* __restrict__ ct, const float* __restrict__ st,
    u16* __restrict__ Qhi, u16* __restrict__ Qlo,
    u16* __restrict__ Khi, u16* __restrict__ Klo,
    u16* __restrict__ Vhi, u16* __restrict__ Vlo)
{
    __shared__ unsigned vtr[64][129];   // proj-2 transpose buffer only

    const int t    = threadIdx.x;
    const int lane = t & 63;
    const int w    = t >> 6;
    const int lx   = lane & 15;
    const int quad = lane >> 4;

    // XCD n-ownership remap (768 blocks, 1D): xcd = lid%8 owns n-panel xcd.
    const int lid  = blockIdx.x;
    const int xcd  = lid & 7;
    const int i_   = lid >> 3;          // 0..95
    const int proj = i_ % 3;
    const int mb   = i_ / 3;            // 0..31
    const int nb   = xcd;
    const int n0   = nb * 128;
    const int m0   = mb * 128;

    const u16* __restrict__ Wph = Whi + (size_t)proj * NW;
    const u16* __restrict__ Wpl = Wlo + (size_t)proj * NW;

    const int am = (w & 1) * 64;
    const int bn = (w >> 1) * 64;
    const int lp = quad * 128 + lx * 8;        // lane part of frag offset

    const u16 *pAh[4], *pAl[4], *pBh[4], *pBl[4];
#pragma unroll
    for (int i = 0; i < 4; i++) {
        const size_t o = ((size_t)(((m0 + am) >> 4) + i) * 32) * 512 + lp;
        pAh[i] = Xhi + o; pAl[i] = Xlo + o;
    }
#pragma unroll
    for (int j = 0; j < 4; j++) {
        const size_t o = ((size_t)(((n0 + bn) >> 4) + j) * 32) * 512 + lp;
        pBh[j] = Wph + o; pBl[j] = Wpl + o;
    }

    f32x4 acc[4][4];
#pragma unroll
    for (int i = 0; i < 4; i++)
#pragma unroll
        for (int j = 0; j < 4; j++) acc[i][j] = (f32x4){0.f, 0.f, 0.f, 0.f};

    bf16x8 cah[4], cal[4], cbh[4], cbl[4];
    bf16x8 nah[4], nal[4], nbh[4], nbl[4];
#pragma unroll
    for (int i = 0; i < 4; i++) { cah[i] = *(const bf16x8*)(pAh[i]); cal[i] = *(const bf16x8*)(pAl[i]); }
#pragma unroll
    for (int j = 0; j < 4; j++) { cbh[j] = *(const bf16x8*)(pBh[j]); cbl[j] = *(const bf16x8*)(pBl[j]); }

#pragma unroll 1
    for (int kt = 0; kt < HID; kt += 64) {
        const int ko1 = ((kt + 32) >> 5) * 512;
        const int ko2 = (kt + 64 < HID) ? ((kt + 64) >> 5) * 512 : 0;

#pragma unroll
        for (int i = 0; i < 4; i++) { nah[i] = *(const bf16x8*)(pAh[i] + ko1); nal[i] = *(const bf16x8*)(pAl[i] + ko1); }
#pragma unroll
        for (int j = 0; j < 4; j++) { nbh[j] = *(const bf16x8*)(pBh[j] + ko1); nbl[j] = *(const bf16x8*)(pBl[j] + ko1); }

        __builtin_amdgcn_s_setprio(1);
#pragma unroll
        for (int j = 0; j < 4; j++)
#pragma unroll
            for (int i = 0; i < 4; i++) {
                acc[i][j] = __builtin_amdgcn_mfma_f32_16x16x32_bf16(cah[i], cbh[j], acc[i][j], 0, 0, 0);
                acc[i][j] = __builtin_amdgcn_mfma_f32_16x16x32_bf16(cal[i], cbh[j], acc[i][j], 0, 0, 0);
                acc[i][j] = __builtin_amdgcn_mfma_f32_16x16x32_bf16(cah[i], cbl[j], acc[i][j], 0, 0, 0);
            }
        __builtin_amdgcn_s_setprio(0);

#pragma unroll
        for (int i = 0; i < 4; i++) { cah[i] = *(const bf16x8*)(pAh[i] + ko2); cal[i] = *(const bf16x8*)(pAl[i] + ko2); }
#pragma unroll
        for (int j = 0; j < 4; j++) { cbh[j] = *(const bf16x8*)(pBh[j] + ko2); cbl[j] = *(const bf16x8*)(pBl[j] + ko2); }

        __builtin_amdgcn_s_setprio(1);
#pragma unroll
        for (int j = 0; j < 4; j++)
#pragma unroll
            for (int i = 0; i < 4; i++) {
                acc[i][j] = __builtin_amdgcn_mfma_f32_16x16x32_bf16(nah[i], nbh[j], acc[i][j], 0, 0, 0);
                acc[i][j] = __builtin_amdgcn_mfma_f32_16x16x32_bf16(nal[i], nbh[j], acc[i][j], 0, 0, 0);
                acc[i][j] = __builtin_amdgcn_mfma_f32_16x16x32_bf16(nah[i], nbl[j], acc[i][j], 0, 0, 0);
            }
        __builtin_amdgcn_s_setprio(0);
    }

    // ---- epilogue ----
    const int b      = m0 >> 11;
    const int head   = (n0 >> 6) + (w >> 1);
    const int m_base = m0 + am;

    if (proj < 2) {
#pragma unroll
        for (int i = 0; i < 4; i++) {
#pragma unroll
            for (int r = 0; r < 4; r++) {
                const int s = (m_base + i * 16 + quad * 4 + r) & 2047;
                const float* ctr = ct + s * HDIM;
                const float* str = st + s * HDIM;
                float nv[4];
#pragma unroll
                for (int j = 0; j < 4; j++) {
                    const int dh = j * 16 + lx;
                    const float c  = ctr[dh];
                    const float sn = str[dh];
                    const float x  = acc[i][j][r];
                    const float p  = acc[i][j ^ 2][r];
                    nv[j] = (j < 2) ? (x * c - p * sn) : (x * c + p * sn);
                }
#pragma unroll
                for (int j = 0; j < 4; j++) acc[i][j][r] = nv[j];
            }
        }
        u16* dh_ = (proj == 0) ? Qhi : Khi;
        u16* dl_ = (proj == 0) ? Qlo : Klo;
        const float qscale = (proj == 0) ? 0.18033688011112042f : 1.0f;
        const size_t obase = (size_t)(b * NHEADS + head) * SEQ * HDIM;
#pragma unroll
        for (int i = 0; i < 4; i++)
#pragma unroll
            for (int r = 0; r < 4; r++) {
                const int s   = (m_base + i * 16 + quad * 4 + r) & 2047;
                const int rb  = s >> 4;
                const int lxq = s & 15;
#pragma unroll
                for (int j = 0; j < 4; j++) {
                    const size_t fo = obase + ((size_t)rb * 2 + (j >> 1)) * 512
                                    + (size_t)((j & 1) * 2 + (lx >> 3)) * 128
                                    + (size_t)lxq * 8 + (lx & 7);
                    u16 hh, ll;
                    split1(acc[i][j][r] * qscale, hh, ll);
                    dh_[fo] = hh;
                    dl_[fo] = ll;
                }
            }
    } else {
#pragma unroll 1
        for (int pass = 0; pass < 2; pass++) {
            __syncthreads();
            if ((w & 1) == pass) {
#pragma unroll
                for (int i = 0; i < 4; i++)
#pragma unroll
                    for (int j = 0; j < 4; j++)
#pragma unroll
                        for (int r = 0; r < 4; r++) {
                            const int ml = i * 16 + quad * 4 + r;
                            const int nl = bn + j * 16 + lx;
                            const float v = acc[i][j][r];
                            unsigned u  = __float_as_uint(v);
                            unsigned hi = u & 0xFFFF0000u;
                            unsigned lo = __float_as_uint(v - __uint_as_float(hi)) >> 16;
                            vtr[ml][nl] = hi | lo;
                        }
            }
            __syncthreads();
            {
                const int d      = t >> 1;            // 0..127 (2 heads x 64)
                const int sh     = (t & 1) * 32;
                const int headv  = (n0 >> 6) + (d >> 6);
                const int dd     = d & 63;
                const size_t vbase = (size_t)(b * NHEADS + headv) * SEQ * HDIM;
                const int s0base = (m0 & 2047) + pass * 64 + sh;
#pragma unroll
                for (int k = 0; k < 4; k++) {
                    const int s0 = s0base + k * 8;
                    u16x8 hv, lv;
#pragma unroll
                    for (int e = 0; e < 8; e++) {
                        unsigned u = vtr[sh + k * 8 + e][d];
                        hv[e] = (u16)(u >> 16);
                        lv[e] = (u16)(u & 0xFFFFu);
                    }
                    const size_t fo = vbase + ((size_t)(dd >> 4) * 64 + (s0 >> 5)) * 512
                                    + (size_t)((s0 >> 3) & 3) * 128 + (size_t)(dd & 15) * 8;
                    *(u16x8*)(Vhi + fo) = hv;
                    *(u16x8*)(Vlo + fo) = lv;
                }
            }
        }
    }
}

// ---------------------------------------------------------------------------
// Flash attention v11: 8-wave (512-thread) blocks, wave = 16 q rows, same
// 128-q tile and grid 512. K/V staged in LDS per kv-tile exactly as v10
// (staging now 3 chunks/thread). With the K double-buffer out of registers
// the per-wave live set (~110 VGPR) allows __launch_bounds__(512,4):
// 16 waves/CU = 4 waves/SIMD — 2x TLP over v10 to hide exp2/split8 VALU
// and LDS latency under other waves' MFMAs. Aggregate MFMA/VALU/staging
// work unchanged; only K-fragment LDS re-reads double (~2% of LDS BW).
// PS[8][16][68] = same 34816 B; LDS total 59392 B (2 blocks/CU = 119 KB).
// Q arrives pre-scaled by log2(e)/8, so scores feed exp2 directly.
// ---------------------------------------------------------------------------
__global__ __launch_bounds__(512, 4) void attn_kernel(
    const u16* __restrict__ Qhi, const u16* __restrict__ Qlo,
    const u16* __restrict__ Khi, const u16* __restrict__ Klo,
    const u16* __restrict__ Vhi, const u16* __restrict__ Vlo,
    float* __restrict__ OUT)
{
    __shared__ __align__(16) u16 KVs[3][4096];   // Khi, Klo, Vhi tiles (24 KB)
    __shared__ float PS[8][16][68];              // 34816 B

    const int t    = threadIdx.x;
    const int lane = t & 63;
    const int w    = t >> 6;                     // 0..7
    const int lx   = lane & 15;
    const int quad = lane >> 4;

    const int q0 = blockIdx.x * 128;
    const int h  = blockIdx.y;
    const int b  = blockIdx.z;
    const size_t base = (size_t)(b * NHEADS + h) * SEQ * HDIM;
    const int lp = quad * 128 + lx * 8;

    // Q fragments (wave w owns q rows [q0 + w*16, q0 + w*16 + 16))
    bf16x8 qh[2], ql[2];
#pragma unroll
    for (int ks = 0; ks < 2; ks++) {
        const size_t fo = base + ((size_t)((q0 >> 4) + w) * 2 + ks) * 512 + lp;
        qh[ks] = *(const bf16x8*)(Qhi + fo);
        ql[ks] = *(const bf16x8*)(Qlo + fo);
    }

    f32x4 O[4];
    float l_part[4];
#pragma unroll
    for (int dt = 0; dt < 4; dt++) O[dt] = (f32x4){0.f,0.f,0.f,0.f};
#pragma unroll
    for (int r = 0; r < 4; r++) l_part[r] = 0.f;

    // --- staging machinery: thread handles 3 16B chunks per tile ---
    // chunk i = plane (0=Khi 1=Klo 2=Vhi), in-plane u16 off o = t*8.
    u16x8 sreg[3];
    auto stage_load = [&](int kt) {
        const int o = t * 8;
        sreg[0] = *(const u16x8*)(Khi + base + (size_t)(kt >> 4) * 1024 + o);
        sreg[1] = *(const u16x8*)(Klo + base + (size_t)(kt >> 4) * 1024 + o);
        const int dt = o >> 10, rem = o & 1023;
        sreg[2] = *(const u16x8*)(Vhi + base + ((size_t)dt * 64 + (kt >> 5)) * 512 + rem);
    };

    stage_load(0);

#pragma unroll 1
    for (int kt = 0; kt < SEQ; kt += 64) {
        __syncthreads();                       // prev body done reading KVs
        {
            const int o = t * 8;
            *(u16x8*)&KVs[0][o] = sreg[0];
            *(u16x8*)&KVs[1][o] = sreg[1];
            *(u16x8*)&KVs[2][o] = sreg[2];
        }
        __syncthreads();                       // staging visible

        // issue next tile's staging loads (consumed at next barrier)
        stage_load((kt + 64) & (SEQ - 1));

        // ---- Vlo fragments: direct global (early issue, consumed in PV) ----
        bf16x8 vl[2][4];
#pragma unroll
        for (int dt = 0; dt < 4; dt++)
#pragma unroll
            for (int ks2 = 0; ks2 < 2; ks2++)
                vl[ks2][dt] = *(const bf16x8*)(Vlo + base + ((size_t)dt * 64 + (kt >> 5) + ks2) * 512 + lp);

        // ---- K fragments from LDS ----
        bf16x8 kh[2][4], kl[2][4];
#pragma unroll
        for (int c = 0; c < 4; c++)
#pragma unroll
            for (int ks = 0; ks < 2; ks++) {
                kh[ks][c] = *(const bf16x8*)&KVs[0][(c * 2 + ks) * 512 + lp];
                kl[ks][c] = *(const bf16x8*)&KVs[1][(c * 2 + ks) * 512 + lp];
            }

        // ---- scores + exp -> PS ----
#pragma unroll
        for (int c = 0; c < 4; c++) {
            f32x4 acc = (f32x4){0.f,0.f,0.f,0.f};
            __builtin_amdgcn_s_setprio(1);
#pragma unroll
            for (int ks = 0; ks < 2; ks++) {
                acc = __builtin_amdgcn_mfma_f32_16x16x32_bf16(qh[ks], kh[ks][c], acc, 0, 0, 0);
                acc = __builtin_amdgcn_mfma_f32_16x16x32_bf16(ql[ks], kh[ks][c], acc, 0, 0, 0);
                acc = __builtin_amdgcn_mfma_f32_16x16x32_bf16(qh[ks], kl[ks][c], acc, 0, 0, 0);
            }
            __builtin_amdgcn_s_setprio(0);
#pragma unroll
            for (int r = 0; r < 4; r++) {
                float p = exp2f(acc[r]);           // Q pre-scaled: 2^(qk*log2e/8)
                l_part[r] += p;
                PS[w][quad * 4 + r][c * 16 + lx] = p;
            }
        }

        // ---- Vhi fragments from LDS ----
        bf16x8 vh[2][4];
#pragma unroll
        for (int dt = 0; dt < 4; dt++)
#pragma unroll
            for (int ks2 = 0; ks2 < 2; ks2++)
                vh[ks2][dt] = *(const bf16x8*)&KVs[2][dt * 1024 + ks2 * 512 + lp];

        // ---- PV ----
#pragma unroll
        for (int ks2 = 0; ks2 < 2; ks2++) {
            const float* ps = &PS[w][lx][ks2 * 32 + quad * 8];
            float pf[8];
            *(float4*)&pf[0] = *(const float4*)ps;
            *(float4*)&pf[4] = *(const float4*)(ps + 4);
            bf16x8 phi, plo;
            split8(pf, phi, plo);
            __builtin_amdgcn_s_setprio(1);
#pragma unroll
            for (int dt = 0; dt < 4; dt++) {
                O[dt] = __builtin_amdgcn_mfma_f32_16x16x32_bf16(phi, vh[ks2][dt], O[dt], 0, 0, 0);
                O[dt] = __builtin_amdgcn_mfma_f32_16x16x32_bf16(plo, vh[ks2][dt], O[dt], 0, 0, 0);
                O[dt] = __builtin_amdgcn_mfma_f32_16x16x32_bf16(phi, vl[ks2][dt], O[dt], 0, 0, 0);
            }
            __builtin_amdgcn_s_setprio(0);
        }
    }

    float linv[4];
#pragma unroll
    for (int r = 0; r < 4; r++) {
        float l = l_part[r];
        l += __shfl_xor(l, 1);
        l += __shfl_xor(l, 2);
        l += __shfl_xor(l, 4);
        l += __shfl_xor(l, 8);
        linv[r] = 1.f / l;
    }

    float* Po = &PS[0][0][0];   // reuse as [128][68]
    __syncthreads();            // all waves done with their PS regions
#pragma unroll
    for (int dt = 0; dt < 4; dt++)
#pragma unroll
        for (int r = 0; r < 4; r++)
            Po[(size_t)(w * 16 + quad * 4 + r) * 68 + dt * 16 + lx] =
                O[dt][r] * linv[r];
    __syncthreads();
    {
        const int q    = t >> 2;       // 0..127
        const int part = t & 3;        // 16 floats each
        const float* prow = Po + (size_t)q * 68 + part * 16;
        float* dst = OUT + ((size_t)(b * SEQ + q0 + q)) * HID + h * HDIM + part * 16;
#pragma unroll
        for (int e = 0; e < 4; e++)
            ((float4*)dst)[e] = ((const float4*)prow)[e];
    }
}

// ---------------------------------------------------------------------------
extern "C" void kernel_launch(void* const* d_in, const int* in_sizes, int n_in,
                              void* d_out, int out_size, void* d_ws, size_t ws_size,
                              hipStream_t stream)
{
    const float* X  = (const float*)d_in[0];
    const float* Wq = (const float*)d_in[1];
    const float* Wk = (const float*)d_in[2];
    const float* Wv = (const float*)d_in[3];
    float* out = (float*)d_out;

    const size_t qkv_elems = (size_t)BATCH * NHEADS * SEQ * HDIM;  // 4,194,304
    char* wsb = (char*)d_ws;
    float* ct  = (float*)wsb;                       // 0.5 MB
    float* st  = ct + (size_t)SEQ * HDIM;           // 0.5 MB
    u16* Xhi = (u16*)(st + (size_t)SEQ * HDIM);     // 8 MB
    u16* Xlo = Xhi + (size_t)NX;                    // 8 MB
    u16* Whi = Xlo + (size_t)NX;                    // 6 MB
    u16* Wlo = Whi + 3 * (size_t)NW;                // 6 MB
    u16* Qhi = Wlo + 3 * (size_t)NW;                // 8 MB
    u16* Qlo = Qhi + qkv_elems;                     // 8 MB
    u16* Khi = Qlo + qkv_elems;                     // 8 MB
    u16* Klo = Khi + qkv_elems;                     // 8 MB
    u16* Vhi = Klo + qkv_elems;                     // 8 MB
    u16* Vlo = Vhi + qkv_elems;                     // 8 MB   (total 77 MB)

    rope_tables_kernel<<<(SEQ * HDIM + 255) / 256, 256, 0, stream>>>(ct, st);

    // 14336 subtiles (8192 X + 3*2048 W), 4 per 256-thread block
    split_kernel<<<3584, 256, 0, stream>>>(
        X, Wq, Wk, Wv, Xhi, Xlo, Whi, Wlo);

    qkv_mfma_kernel<<<dim3(3 * (HID / 128) * ((BATCH * SEQ) / 128)), 256, 0, stream>>>(
        Xhi, Xlo, Whi, Wlo, ct, st, Qhi, Qlo, Khi, Klo, Vhi, Vlo);

    attn_kernel<<<dim3(SEQ / 128, NHEADS, BATCH), 512, 0, stream>>>(
        Qhi, Qlo, Khi, Klo, Vhi, Vlo, out);
}

// Round 12
// 272.163 us; speedup vs baseline: 1.8437x; 1.8437x over previous
//
#include <hip/hip_runtime.h>
#include <math.h>

#define NHEADS 16
#define HDIM   64
#define HID    1024
#define BATCH  2
#define SEQ    2048
#define NX (BATCH*SEQ*HID)       // 4194304
#define NW (HID*HID)             // 1048576

typedef unsigned short u16;
typedef __attribute__((ext_vector_type(8))) short  bf16x8;   // 8 bf16 = 4 VGPR
typedef __attribute__((ext_vector_type(8))) unsigned short u16x8;
typedef __attribute__((ext_vector_type(4))) float  f32x4;

// ---------------------------------------------------------------------------
// Fragment-tiled layout ("FT"): operand rows r, inner dim k. Subtile =
// 16 rows x 32 k. Element (r,k) lives at
//   ((r>>4)*KB + (k>>5))*512 + ((k>>3)&3)*128 + (r&15)*8 + (k&7)     [u16]
// (KB = k-blocks per row-block row). A wave's MFMA fragment load
// (lane = quad*16+lx -> 16B) is then 64 lanes x 16B CONTIGUOUS.
// hi / lo planes are separate arrays (keeps lane stride 16B).
// ---------------------------------------------------------------------------

// v_perm-based split: hi pair = bytes[2,3] of each fp32 (truncated bf16),
// lo pair = bytes[2,3] of (p - hi) — numerically identical to shift form.
__device__ __forceinline__ void split8(const float* xf, bf16x8& hi, bf16x8& lo) {
    unsigned* hp = (unsigned*)&hi;
    unsigned* lp = (unsigned*)&lo;
#pragma unroll
    for (int j = 0; j < 4; j++) {
        const float p0 = xf[2 * j], p1 = xf[2 * j + 1];
        const unsigned u0 = __float_as_uint(p0);
        const unsigned u1 = __float_as_uint(p1);
        hp[j] = __builtin_amdgcn_perm(u1, u0, 0x07060302u);
        const float l0 = p0 - __uint_as_float(u0 & 0xFFFF0000u);
        const float l1 = p1 - __uint_as_float(u1 & 0xFFFF0000u);
        lp[j] = __builtin_amdgcn_perm(__float_as_uint(l1), __float_as_uint(l0), 0x07060302u);
    }
}
__device__ __forceinline__ void split1(float v, u16& h, u16& l) {
    unsigned u = __float_as_uint(v);
    h = (u16)(u >> 16);
    l = (u16)(__float_as_uint(v - __uint_as_float(u & 0xFFFF0000u)) >> 16);
}

// ---------------------------------------------------------------------------
// RoPE tables
// ---------------------------------------------------------------------------
__global__ void rope_tables_kernel(float* __restrict__ ct, float* __restrict__ st) {
    int idx = blockIdx.x * 256 + threadIdx.x;
    if (idx >= SEQ * HDIM) return;
    int s  = idx >> 6;
    int dh = idx & 63;
    int i  = dh & 31;
    float inv = exp2f(-(float)i * (13.28771237954945f / 32.0f));  // log2(10000)/32
    float fr  = (float)s * inv;
    ct[idx] = cosf(fr);
    st[idx] = sinf(fr);
}

// ---------------------------------------------------------------------------
// Pre-pass v2 (unchanged from round 9): one wave per 512-u16 subtile,
// coalesced 1KB wave-stores.
// ---------------------------------------------------------------------------
__global__ __launch_bounds__(256) void split_kernel(
    const float* __restrict__ X,
    const float* __restrict__ W0,
    const float* __restrict__ W1,
    const float* __restrict__ W2,
    u16* __restrict__ Xhi, u16* __restrict__ Xlo,
    u16* __restrict__ Whi, u16* __restrict__ Wlo)
{
    const int s = blockIdx.x * 4 + (threadIdx.x >> 6);
    const int l = threadIdx.x & 63;
    const int r = l & 15, q = l >> 4;
    const float* src; u16* dh; u16* dl; int so;
    if (s < 8192) { src = X; dh = Xhi; dl = Xlo; so = s; }
    else {
        const int wi = (s - 8192) >> 11;
        so = (s - 8192) & 2047;
        src = (wi == 0) ? W0 : ((wi == 1) ? W1 : W2);
        dh = Whi + (size_t)wi * NW;
        dl = Wlo + (size_t)wi * NW;
    }
    const int R0 = (so >> 5) << 4, K0 = (so & 31) << 5;
    const float* sp = src + (size_t)(R0 + r) * 1024 + K0 + q * 8;
    float v[8];
    *(float4*)&v[0] = *(const float4*)sp;
    *(float4*)&v[4] = *(const float4*)(sp + 4);
    u16x8 h8, l8;
#pragma unroll
    for (int e = 0; e < 8; e++) {
        u16 hh, ll;
        split1(v[e], hh, ll);
        h8[e] = hh; l8[e] = ll;
    }
    const size_t off = (size_t)so * 512 + l * 8;
    *(u16x8*)(dh + off) = h8;
    *(u16x8*)(dl + off) = l8;
}

// ---------------------------------------------------------------------------
// MFMA QKV GEMM (round-6 structure). ko2 is UNCONDITIONAL (linear) so the
// prefetch pointers strength-reduce; the final iteration's c-buffer prefetch
// overreads one k-block into the ADJACENT workspace plane (allocated,
// never consumed — the loop exits before those buffers feed an MFMA).
// ---------------------------------------------------------------------------
__global__ __launch_bounds__(256, 2) void qkv_mfma_kernel(
    const u16* __restrict__ Xhi, const u16* __restrict__ Xlo,
    const u16* __restrict__ Whi, const u16* __restrict__ Wlo,
    const float* __restrict__ ct, const float* __restrict__ st,
    u16* __restrict__ Qhi, u16* __restrict__ Qlo,
    u16* __restrict__ Khi, u16* __restrict__ Klo,
    u16* __restrict__ Vhi, u16* __restrict__ Vlo)
{
    __shared__ unsigned vtr[64][129];   // proj-2 transpose buffer only

    const int t    = threadIdx.x;
    const int lane = t & 63;
    const int w    = t >> 6;
    const int lx   = lane & 15;
    const int quad = lane >> 4;

    // XCD n-ownership remap (768 blocks, 1D): xcd = lid%8 owns n-panel xcd.
    const int lid  = blockIdx.x;
    const int xcd  = lid & 7;
    const int i_   = lid >> 3;          // 0..95
    const int proj = i_ % 3;
    const int mb   = i_ / 3;            // 0..31
    const int nb   = xcd;
    const int n0   = nb * 128;
    const int m0   = mb * 128;

    const u16* __restrict__ Wph = Whi + (size_t)proj * NW;
    const u16* __restrict__ Wpl = Wlo + (size_t)proj * NW;

    const int am = (w & 1) * 64;
    const int bn = (w >> 1) * 64;
    const int lp = quad * 128 + lx * 8;        // lane part of frag offset

    const u16 *pAh[4], *pAl[4], *pBh[4], *pBl[4];
#pragma unroll
    for (int i = 0; i < 4; i++) {
        const size_t o = ((size_t)(((m0 + am) >> 4) + i) * 32) * 512 + lp;
        pAh[i] = Xhi + o; pAl[i] = Xlo + o;
    }
#pragma unroll
    for (int j = 0; j < 4; j++) {
        const size_t o = ((size_t)(((n0 + bn) >> 4) + j) * 32) * 512 + lp;
        pBh[j] = Wph + o; pBl[j] = Wpl + o;
    }

    f32x4 acc[4][4];
#pragma unroll
    for (int i = 0; i < 4; i++)
#pragma unroll
        for (int j = 0; j < 4; j++) acc[i][j] = (f32x4){0.f, 0.f, 0.f, 0.f};

    bf16x8 cah[4], cal[4], cbh[4], cbl[4];
    bf16x8 nah[4], nal[4], nbh[4], nbl[4];
#pragma unroll
    for (int i = 0; i < 4; i++) { cah[i] = *(const bf16x8*)(pAh[i]); cal[i] = *(const bf16x8*)(pAl[i]); }
#pragma unroll
    for (int j = 0; j < 4; j++) { cbh[j] = *(const bf16x8*)(pBh[j]); cbl[j] = *(const bf16x8*)(pBl[j]); }

#pragma unroll 1
    for (int kt = 0; kt < HID; kt += 64) {
        const int ko1 = ((kt + 32) >> 5) * 512;
        const int ko2 = ((kt + 64) >> 5) * 512;   // linear; last-iter overread is benign

#pragma unroll
        for (int i = 0; i < 4; i++) { nah[i] = *(const bf16x8*)(pAh[i] + ko1); nal[i] = *(const bf16x8*)(pAl[i] + ko1); }
#pragma unroll
        for (int j = 0; j < 4; j++) { nbh[j] = *(const bf16x8*)(pBh[j] + ko1); nbl[j] = *(const bf16x8*)(pBl[j] + ko1); }

        __builtin_amdgcn_s_setprio(1);
#pragma unroll
        for (int j = 0; j < 4; j++)
#pragma unroll
            for (int i = 0; i < 4; i++) {
                acc[i][j] = __builtin_amdgcn_mfma_f32_16x16x32_bf16(cah[i], cbh[j], acc[i][j], 0, 0, 0);
                acc[i][j] = __builtin_amdgcn_mfma_f32_16x16x32_bf16(cal[i], cbh[j], acc[i][j], 0, 0, 0);
                acc[i][j] = __builtin_amdgcn_mfma_f32_16x16x32_bf16(cah[i], cbl[j], acc[i][j], 0, 0, 0);
            }
        __builtin_amdgcn_s_setprio(0);

#pragma unroll
        for (int i = 0; i < 4; i++) { cah[i] = *(const bf16x8*)(pAh[i] + ko2); cal[i] = *(const bf16x8*)(pAl[i] + ko2); }
#pragma unroll
        for (int j = 0; j < 4; j++) { cbh[j] = *(const bf16x8*)(pBh[j] + ko2); cbl[j] = *(const bf16x8*)(pBl[j] + ko2); }

        __builtin_amdgcn_s_setprio(1);
#pragma unroll
        for (int j = 0; j < 4; j++)
#pragma unroll
            for (int i = 0; i < 4; i++) {
                acc[i][j] = __builtin_amdgcn_mfma_f32_16x16x32_bf16(nah[i], nbh[j], acc[i][j], 0, 0, 0);
                acc[i][j] = __builtin_amdgcn_mfma_f32_16x16x32_bf16(nal[i], nbh[j], acc[i][j], 0, 0, 0);
                acc[i][j] = __builtin_amdgcn_mfma_f32_16x16x32_bf16(nah[i], nbl[j], acc[i][j], 0, 0, 0);
            }
        __builtin_amdgcn_s_setprio(0);
    }

    // ---- epilogue ----
    const int b      = m0 >> 11;
    const int head   = (n0 >> 6) + (w >> 1);
    const int m_base = m0 + am;

    if (proj < 2) {
#pragma unroll
        for (int i = 0; i < 4; i++) {
#pragma unroll
            for (int r = 0; r < 4; r++) {
                const int s = (m_base + i * 16 + quad * 4 + r) & 2047;
                const float* ctr = ct + s * HDIM;
                const float* str = st + s * HDIM;
                float nv[4];
#pragma unroll
                for (int j = 0; j < 4; j++) {
                    const int dh = j * 16 + lx;
                    const float c  = ctr[dh];
                    const float sn = str[dh];
                    const float x  = acc[i][j][r];
                    const float p  = acc[i][j ^ 2][r];
                    nv[j] = (j < 2) ? (x * c - p * sn) : (x * c + p * sn);
                }
#pragma unroll
                for (int j = 0; j < 4; j++) acc[i][j][r] = nv[j];
            }
        }
        u16* dh_ = (proj == 0) ? Qhi : Khi;
        u16* dl_ = (proj == 0) ? Qlo : Klo;
        const float qscale = (proj == 0) ? 0.18033688011112042f : 1.0f;
        const size_t obase = (size_t)(b * NHEADS + head) * SEQ * HDIM;
#pragma unroll
        for (int i = 0; i < 4; i++)
#pragma unroll
            for (int r = 0; r < 4; r++) {
                const int s   = (m_base + i * 16 + quad * 4 + r) & 2047;
                const int rb  = s >> 4;
                const int lxq = s & 15;
#pragma unroll
                for (int j = 0; j < 4; j++) {
                    const size_t fo = obase + ((size_t)rb * 2 + (j >> 1)) * 512
                                    + (size_t)((j & 1) * 2 + (lx >> 3)) * 128
                                    + (size_t)lxq * 8 + (lx & 7);
                    u16 hh, ll;
                    split1(acc[i][j][r] * qscale, hh, ll);
                    dh_[fo] = hh;
                    dl_[fo] = ll;
                }
            }
    } else {
#pragma unroll 1
        for (int pass = 0; pass < 2; pass++) {
            __syncthreads();
            if ((w & 1) == pass) {
#pragma unroll
                for (int i = 0; i < 4; i++)
#pragma unroll
                    for (int j = 0; j < 4; j++)
#pragma unroll
                        for (int r = 0; r < 4; r++) {
                            const int ml = i * 16 + quad * 4 + r;
                            const int nl = bn + j * 16 + lx;
                            const float v = acc[i][j][r];
                            unsigned u  = __float_as_uint(v);
                            unsigned hi = u & 0xFFFF0000u;
                            unsigned lo = __float_as_uint(v - __uint_as_float(hi)) >> 16;
                            vtr[ml][nl] = hi | lo;
                        }
            }
            __syncthreads();
            {
                const int d      = t >> 1;            // 0..127 (2 heads x 64)
                const int sh     = (t & 1) * 32;
                const int headv  = (n0 >> 6) + (d >> 6);
                const int dd     = d & 63;
                const size_t vbase = (size_t)(b * NHEADS + headv) * SEQ * HDIM;
                const int s0base = (m0 & 2047) + pass * 64 + sh;
#pragma unroll
                for (int k = 0; k < 4; k++) {
                    const int s0 = s0base + k * 8;
                    u16x8 hv, lv;
#pragma unroll
                    for (int e = 0; e < 8; e++) {
                        unsigned u = vtr[sh + k * 8 + e][d];
                        hv[e] = (u16)(u >> 16);
                        lv[e] = (u16)(u & 0xFFFFu);
                    }
                    const size_t fo = vbase + ((size_t)(dd >> 4) * 64 + (s0 >> 5)) * 512
                                    + (size_t)((s0 >> 3) & 3) * 128 + (size_t)(dd & 15) * 8;
                    *(u16x8*)(Vhi + fo) = hv;
                    *(u16x8*)(Vlo + fo) = lv;
                }
            }
        }
    }
}

// ---------------------------------------------------------------------------
// Flash attention v13 = round-9 v10 (verified 131.5 us) + linear-pointer
// VALU diet, with staging CORRECTLY kept at 6 chunks/thread (256 threads x
// 8 u16 x 2 halves = 4096 u16 per plane — round 11's NaN was 3 chunks =
// half-staged planes). Six staging pointers advance by constant strides
// (K planes +4096/tile, Vhi +1024/tile); final prefetch overreads into the
// adjacent allocated plane and is never consumed. Vlo fragment pointers
// precomputed (8) and incremented by 1024/tile.
// launch_bounds STAYS (256,2): rounds 1/10 proved tighter bounds destroy
// the register pipeline (VGPR 64 -> 1 GB scratch traffic).
// ---------------------------------------------------------------------------
__global__ __launch_bounds__(256, 2) void attn_kernel(
    const u16* __restrict__ Qhi, const u16* __restrict__ Qlo,
    const u16* __restrict__ Khi, const u16* __restrict__ Klo,
    const u16* __restrict__ Vhi, const u16* __restrict__ Vlo,
    float* __restrict__ OUT)
{
    __shared__ __align__(16) u16 KVs[3][4096];   // Khi, Klo, Vhi tiles (24 KB)
    __shared__ float PS[4][32][68];              // 34816 B

    const int t    = threadIdx.x;
    const int lane = t & 63;
    const int w    = t >> 6;
    const int lx   = lane & 15;
    const int quad = lane >> 4;

    const int q0 = blockIdx.x * 128;
    const int h  = blockIdx.y;
    const int b  = blockIdx.z;
    const size_t base = (size_t)(b * NHEADS + h) * SEQ * HDIM;
    const int lp = quad * 128 + lx * 8;

    // Q fragments (already split + pre-scaled in workspace)
    bf16x8 qh[2][2], ql[2][2];
#pragma unroll
    for (int a = 0; a < 2; a++)
#pragma unroll
        for (int ks = 0; ks < 2; ks++) {
            const size_t fo = base + ((size_t)((q0 >> 4) + w * 2 + a) * 2 + ks) * 512 + lp;
            qh[a][ks] = *(const bf16x8*)(Qhi + fo);
            ql[a][ks] = *(const bf16x8*)(Qlo + fo);
        }

    f32x4 O[2][4];
    float l_part[2][4];
#pragma unroll
    for (int a = 0; a < 2; a++) {
#pragma unroll
        for (int dt = 0; dt < 4; dt++) O[a][dt] = (f32x4){0.f,0.f,0.f,0.f};
#pragma unroll
        for (int r = 0; r < 4; r++) l_part[a][r] = 0.f;
    }

    // --- staging machinery: 6 chunks/thread (2 halves x 3 planes), linear
    // pointers with constant strides ---
    const int o0 = t * 8;            // [0,2048)
    const int o1 = o0 + 2048;        // [2048,4096)
    const u16* pKh0 = Khi + base + o0;
    const u16* pKh1 = Khi + base + o1;
    const u16* pKl0 = Klo + base + o0;
    const u16* pKl1 = Klo + base + o1;
    const u16* pVh0 = Vhi + base + ((size_t)(o0 >> 10) * 64) * 512 + (o0 & 1023);
    const u16* pVh1 = Vhi + base + ((size_t)(o1 >> 10) * 64) * 512 + (o1 & 1023);
    u16x8 sreg[6];
    auto stage_load = [&]() {
        sreg[0] = *(const u16x8*)pKh0;  pKh0 += 4096;   // K tile stride
        sreg[1] = *(const u16x8*)pKh1;  pKh1 += 4096;
        sreg[2] = *(const u16x8*)pKl0;  pKl0 += 4096;
        sreg[3] = *(const u16x8*)pKl1;  pKl1 += 4096;
        sreg[4] = *(const u16x8*)pVh0;  pVh0 += 1024;   // V tile stride
        sreg[5] = *(const u16x8*)pVh1;  pVh1 += 1024;
    };

    // --- Vlo fragment pointers: 8 linear pointers, +1024/tile ---
    const u16* pVl[2][4];
#pragma unroll
    for (int dt = 0; dt < 4; dt++)
#pragma unroll
        for (int ks2 = 0; ks2 < 2; ks2++)
            pVl[ks2][dt] = Vlo + base + ((size_t)dt * 64 + ks2) * 512 + lp;

    stage_load();

#pragma unroll 1
    for (int kt = 0; kt < SEQ; kt += 64) {
        __syncthreads();                       // prev body done reading KVs
        {
            *(u16x8*)&KVs[0][o0] = sreg[0];
            *(u16x8*)&KVs[0][o1] = sreg[1];
            *(u16x8*)&KVs[1][o0] = sreg[2];
            *(u16x8*)&KVs[1][o1] = sreg[3];
            *(u16x8*)&KVs[2][o0] = sreg[4];
            *(u16x8*)&KVs[2][o1] = sreg[5];
        }
        __syncthreads();                       // staging visible

        // issue next tile's staging loads (consumed at next barrier;
        // final iteration overreads into the adjacent plane, never consumed)
        stage_load();

        // ---- Vlo fragments: direct global (early issue, consumed in PV) ----
        bf16x8 vl[2][4];
#pragma unroll
        for (int dt = 0; dt < 4; dt++)
#pragma unroll
            for (int ks2 = 0; ks2 < 2; ks2++) {
                vl[ks2][dt] = *(const bf16x8*)pVl[ks2][dt];
                pVl[ks2][dt] += 1024;
            }

        // ---- K fragments from LDS ----
        bf16x8 kh[2][4], kl[2][4];
#pragma unroll
        for (int c = 0; c < 4; c++)
#pragma unroll
            for (int ks = 0; ks < 2; ks++) {
                kh[ks][c] = *(const bf16x8*)&KVs[0][(c * 2 + ks) * 512 + lp];
                kl[ks][c] = *(const bf16x8*)&KVs[1][(c * 2 + ks) * 512 + lp];
            }

        // ---- scores + exp -> PS ----
#pragma unroll
        for (int a = 0; a < 2; a++) {
#pragma unroll
            for (int c = 0; c < 4; c++) {
                f32x4 acc = (f32x4){0.f,0.f,0.f,0.f};
                __builtin_amdgcn_s_setprio(1);
#pragma unroll
                for (int ks = 0; ks < 2; ks++) {
                    acc = __builtin_amdgcn_mfma_f32_16x16x32_bf16(qh[a][ks], kh[ks][c], acc, 0, 0, 0);
                    acc = __builtin_amdgcn_mfma_f32_16x16x32_bf16(ql[a][ks], kh[ks][c], acc, 0, 0, 0);
                    acc = __builtin_amdgcn_mfma_f32_16x16x32_bf16(qh[a][ks], kl[ks][c], acc, 0, 0, 0);
                }
                __builtin_amdgcn_s_setprio(0);
#pragma unroll
                for (int r = 0; r < 4; r++) {
                    float p = exp2f(acc[r]);           // Q pre-scaled: 2^(qk*log2e/8)
                    l_part[a][r] += p;
                    PS[w][a * 16 + quad * 4 + r][c * 16 + lx] = p;
                }
            }
        }

        // ---- Vhi fragments from LDS ----
        bf16x8 vh[2][4];
#pragma unroll
        for (int dt = 0; dt < 4; dt++)
#pragma unroll
            for (int ks2 = 0; ks2 < 2; ks2++)
                vh[ks2][dt] = *(const bf16x8*)&KVs[2][dt * 1024 + ks2 * 512 + lp];

        // ---- PV ----
#pragma unroll
        for (int a = 0; a < 2; a++) {
#pragma unroll
            for (int ks2 = 0; ks2 < 2; ks2++) {
                const float* ps = &PS[w][a * 16 + lx][ks2 * 32 + quad * 8];
                float pf[8];
                *(float4*)&pf[0] = *(const float4*)ps;
                *(float4*)&pf[4] = *(const float4*)(ps + 4);
                bf16x8 phi, plo;
                split8(pf, phi, plo);
                __builtin_amdgcn_s_setprio(1);
#pragma unroll
                for (int dt = 0; dt < 4; dt++) {
                    O[a][dt] = __builtin_amdgcn_mfma_f32_16x16x32_bf16(phi, vh[ks2][dt], O[a][dt], 0, 0, 0);
                    O[a][dt] = __builtin_amdgcn_mfma_f32_16x16x32_bf16(plo, vh[ks2][dt], O[a][dt], 0, 0, 0);
                    O[a][dt] = __builtin_amdgcn_mfma_f32_16x16x32_bf16(phi, vl[ks2][dt], O[a][dt], 0, 0, 0);
                }
                __builtin_amdgcn_s_setprio(0);
            }
        }
    }

    float linv[2][4];
#pragma unroll
    for (int a = 0; a < 2; a++)
#pragma unroll
        for (int r = 0; r < 4; r++) {
            float l = l_part[a][r];
            l += __shfl_xor(l, 1);
            l += __shfl_xor(l, 2);
            l += __shfl_xor(l, 4);
            l += __shfl_xor(l, 8);
            linv[a][r] = 1.f / l;
        }

    float* Po = &PS[0][0][0];   // reuse as [128][68]
    __syncthreads();            // all waves done with their PS regions
#pragma unroll
    for (int a = 0; a < 2; a++)
#pragma unroll
        for (int dt = 0; dt < 4; dt++)
#pragma unroll
            for (int r = 0; r < 4; r++)
                Po[(size_t)(w * 32 + a * 16 + quad * 4 + r) * 68 + dt * 16 + lx] =
                    O[a][dt][r] * linv[a][r];
    __syncthreads();
    {
        const int q    = t >> 1;
        const int half = t & 1;
        const float* prow = Po + (size_t)q * 68 + half * 32;
        float* dst = OUT + ((size_t)(b * SEQ + q0 + q)) * HID + h * HDIM + half * 32;
#pragma unroll
        for (int e = 0; e < 8; e++)
            ((float4*)dst)[e] = ((const float4*)prow)[e];
    }
}

// ---------------------------------------------------------------------------
extern "C" void kernel_launch(void* const* d_in, const int* in_sizes, int n_in,
                              void* d_out, int out_size, void* d_ws, size_t ws_size,
                              hipStream_t stream)
{
    const float* X  = (const float*)d_in[0];
    const float* Wq = (const float*)d_in[1];
    const float* Wk = (const float*)d_in[2];
    const float* Wv = (const float*)d_in[3];
    float* out = (float*)d_out;

    const size_t qkv_elems = (size_t)BATCH * NHEADS * SEQ * HDIM;  // 4,194,304
    char* wsb = (char*)d_ws;
    float* ct  = (float*)wsb;                       // 0.5 MB
    float* st  = ct + (size_t)SEQ * HDIM;           // 0.5 MB
    u16* Xhi = (u16*)(st + (size_t)SEQ * HDIM);     // 8 MB
    u16* Xlo = Xhi + (size_t)NX;                    // 8 MB
    u16* Whi = Xlo + (size_t)NX;                    // 6 MB
    u16* Wlo = Whi + 3 * (size_t)NW;                // 6 MB
    u16* Qhi = Wlo + 3 * (size_t)NW;                // 8 MB
    u16* Qlo = Qhi + qkv_elems;                     // 8 MB
    u16* Khi = Qlo + qkv_elems;                     // 8 MB
    u16* Klo = Khi + qkv_elems;                     // 8 MB
    u16* Vhi = Klo + qkv_elems;                     // 8 MB
    u16* Vlo = Vhi + qkv_elems;                     // 8 MB   (total 77 MB)

    rope_tables_kernel<<<(SEQ * HDIM + 255) / 256, 256, 0, stream>>>(ct, st);

    // 14336 subtiles (8192 X + 3*2048 W), 4 per 256-thread block
    split_kernel<<<3584, 256, 0, stream>>>(
        X, Wq, Wk, Wv, Xhi, Xlo, Whi, Wlo);

    qkv_mfma_kernel<<<dim3(3 * (HID / 128) * ((BATCH * SEQ) / 128)), 256, 0, stream>>>(
        Xhi, Xlo, Whi, Wlo, ct, st, Qhi, Qlo, Khi, Klo, Vhi, Vlo);

    attn_kernel<<<dim3(SEQ / 128, NHEADS, BATCH), 256, 0, stream>>>(
        Qhi, Qlo, Khi, Klo, Vhi, Vlo, out);
}

// Round 13
// 270.888 us; speedup vs baseline: 1.8524x; 1.0047x over previous
//
#include <hip/hip_runtime.h>
#include <math.h>

#define NHEADS 16
#define HDIM   64
#define HID    1024
#define BATCH  2
#define SEQ    2048
#define NX (BATCH*SEQ*HID)       // 4194304
#define NW (HID*HID)             // 1048576

typedef unsigned short u16;
typedef __attribute__((ext_vector_type(8))) short  bf16x8;   // 8 bf16 = 4 VGPR
typedef __attribute__((ext_vector_type(8))) unsigned short u16x8;
typedef __attribute__((ext_vector_type(4))) float  f32x4;

// ---------------------------------------------------------------------------
// Fragment-tiled layout ("FT"): operand rows r, inner dim k. Subtile =
// 16 rows x 32 k. Element (r,k) lives at
//   ((r>>4)*KB + (k>>5))*512 + ((k>>3)&3)*128 + (r&15)*8 + (k&7)     [u16]
// (KB = k-blocks per row-block row). A wave's MFMA fragment load
// (lane = quad*16+lx -> 16B) is then 64 lanes x 16B CONTIGUOUS.
// hi / lo planes are separate arrays (keeps lane stride 16B).
// ---------------------------------------------------------------------------

// v_perm-based split: hi pair = bytes[2,3] of each fp32 (truncated bf16),
// lo pair = bytes[2,3] of (p - hi) — numerically identical to shift form.
__device__ __forceinline__ void split8(const float* xf, bf16x8& hi, bf16x8& lo) {
    unsigned* hp = (unsigned*)&hi;
    unsigned* lp = (unsigned*)&lo;
#pragma unroll
    for (int j = 0; j < 4; j++) {
        const float p0 = xf[2 * j], p1 = xf[2 * j + 1];
        const unsigned u0 = __float_as_uint(p0);
        const unsigned u1 = __float_as_uint(p1);
        hp[j] = __builtin_amdgcn_perm(u1, u0, 0x07060302u);
        const float l0 = p0 - __uint_as_float(u0 & 0xFFFF0000u);
        const float l1 = p1 - __uint_as_float(u1 & 0xFFFF0000u);
        lp[j] = __builtin_amdgcn_perm(__float_as_uint(l1), __float_as_uint(l0), 0x07060302u);
    }
}
__device__ __forceinline__ void split1(float v, u16& h, u16& l) {
    unsigned u = __float_as_uint(v);
    h = (u16)(u >> 16);
    l = (u16)(__float_as_uint(v - __uint_as_float(u & 0xFFFF0000u)) >> 16);
}

// ---------------------------------------------------------------------------
// RoPE tables
// ---------------------------------------------------------------------------
__global__ void rope_tables_kernel(float* __restrict__ ct, float* __restrict__ st) {
    int idx = blockIdx.x * 256 + threadIdx.x;
    if (idx >= SEQ * HDIM) return;
    int s  = idx >> 6;
    int dh = idx & 63;
    int i  = dh & 31;
    float inv = exp2f(-(float)i * (13.28771237954945f / 32.0f));  // log2(10000)/32
    float fr  = (float)s * inv;
    ct[idx] = cosf(fr);
    st[idx] = sinf(fr);
}

// ---------------------------------------------------------------------------
// Pre-pass v2 (unchanged): one wave per 512-u16 subtile, coalesced 1KB
// wave-stores.
// ---------------------------------------------------------------------------
__global__ __launch_bounds__(256) void split_kernel(
    const float* __restrict__ X,
    const float* __restrict__ W0,
    const float* __restrict__ W1,
    const float* __restrict__ W2,
    u16* __restrict__ Xhi, u16* __restrict__ Xlo,
    u16* __restrict__ Whi, u16* __restrict__ Wlo)
{
    const int s = blockIdx.x * 4 + (threadIdx.x >> 6);
    const int l = threadIdx.x & 63;
    const int r = l & 15, q = l >> 4;
    const float* src; u16* dh; u16* dl; int so;
    if (s < 8192) { src = X; dh = Xhi; dl = Xlo; so = s; }
    else {
        const int wi = (s - 8192) >> 11;
        so = (s - 8192) & 2047;
        src = (wi == 0) ? W0 : ((wi == 1) ? W1 : W2);
        dh = Whi + (size_t)wi * NW;
        dl = Wlo + (size_t)wi * NW;
    }
    const int R0 = (so >> 5) << 4, K0 = (so & 31) << 5;
    const float* sp = src + (size_t)(R0 + r) * 1024 + K0 + q * 8;
    float v[8];
    *(float4*)&v[0] = *(const float4*)sp;
    *(float4*)&v[4] = *(const float4*)(sp + 4);
    u16x8 h8, l8;
#pragma unroll
    for (int e = 0; e < 8; e++) {
        u16 hh, ll;
        split1(v[e], hh, ll);
        h8[e] = hh; l8[e] = ll;
    }
    const size_t off = (size_t)so * 512 + l * 8;
    *(u16x8*)(dh + off) = h8;
    *(u16x8*)(dl + off) = l8;
}

// ---------------------------------------------------------------------------
// MFMA QKV GEMM v9: LDS-staged fragments (round-9 attn pattern ported).
// Per 32-k step, the 128x32 A-tile (hi+lo, 16 KB) and B-tile (16 KB) are
// register-staged (8 chunks/thread, 2 linear global pointers +512/step)
// and ds_written after the barrier; all 4 waves then ds_read_b128 their
// fragments — removes the 2x intra-block redundant global fragment loads
// and the 16-pointer vmcnt pipeline. Staging buffer (32 KB) OVERLAYS the
// proj-2 vtr transpose buffer (33 KB; only live in the epilogue, which
// begins with __syncthreads). Last-iteration prefetch overreads into the
// adjacent allocated workspace plane (never consumed).
// XCD n-ownership remap + s_setprio kept.
// ---------------------------------------------------------------------------
__global__ __launch_bounds__(256, 2) void qkv_mfma_kernel(
    const u16* __restrict__ Xhi, const u16* __restrict__ Xlo,
    const u16* __restrict__ Whi, const u16* __restrict__ Wlo,
    const float* __restrict__ ct, const float* __restrict__ st,
    u16* __restrict__ Qhi, u16* __restrict__ Qlo,
    u16* __restrict__ Khi, u16* __restrict__ Klo,
    u16* __restrict__ Vhi, u16* __restrict__ Vlo)
{
    __shared__ __align__(16) unsigned char SMEMRAW[64 * 129 * 4];  // 33024 B
    u16* SM = (u16*)SMEMRAW;                       // staging view: 16384 u16
    unsigned (*vtr)[129] = (unsigned (*)[129])SMEMRAW;  // epilogue view

    const int t    = threadIdx.x;
    const int lane = t & 63;
    const int w    = t >> 6;
    const int lx   = lane & 15;
    const int quad = lane >> 4;

    // XCD n-ownership remap (768 blocks, 1D): xcd = lid%8 owns n-panel xcd.
    const int lid  = blockIdx.x;
    const int xcd  = lid & 7;
    const int i_   = lid >> 3;          // 0..95
    const int proj = i_ % 3;
    const int mb   = i_ / 3;            // 0..31
    const int nb   = xcd;
    const int n0   = nb * 128;
    const int m0   = mb * 128;

    const u16* __restrict__ Wph = Whi + (size_t)proj * NW;

    const int am = (w & 1) * 64;
    const int bn = (w >> 1) * 64;
    const int lp = quad * 128 + lx * 8;        // lane part of frag offset

    // --- staging pointers: thread t covers subtile si = t>>6 (and si+4 via
    // +65536 offset), in-subtile offset (t&63)*8; +512 per 32-k step ---
    const int si  = t >> 6;
    const int sio = (t & 63) * 8;
    const u16* pA = Xhi + (size_t)((m0 >> 4) + si) * 32 * 512 + sio;
    const u16* pB = Wph + (size_t)((n0 >> 4) + si) * 32 * 512 + sio;
    u16x8 sreg[8];
    auto stage_load = [&]() {
        sreg[0] = *(const u16x8*)(pA);                            // A_hi si
        sreg[1] = *(const u16x8*)(pA + 65536);                    // A_hi si+4
        sreg[2] = *(const u16x8*)(pA + (size_t)NX);               // A_lo si
        sreg[3] = *(const u16x8*)(pA + (size_t)NX + 65536);       // A_lo si+4
        sreg[4] = *(const u16x8*)(pB);                            // B_hi si
        sreg[5] = *(const u16x8*)(pB + 65536);                    // B_hi si+4
        sreg[6] = *(const u16x8*)(pB + 3 * (size_t)NW);           // B_lo si
        sreg[7] = *(const u16x8*)(pB + 3 * (size_t)NW + 65536);   // B_lo si+4
        pA += 512; pB += 512;
    };

    f32x4 acc[4][4];
#pragma unroll
    for (int i = 0; i < 4; i++)
#pragma unroll
        for (int j = 0; j < 4; j++) acc[i][j] = (f32x4){0.f, 0.f, 0.f, 0.f};

    // LDS fragment bases: A_hi 0, A_lo 4096, B_hi 8192, B_lo 12288
    const int aoff = (w & 1) * 4 * 512;
    const int boff = 8192 + (w >> 1) * 4 * 512;

    stage_load();   // k-block 0

#pragma unroll 1
    for (int kt = 0; kt < HID; kt += 32) {
        __syncthreads();                       // prev step's reads done
        {
            const int L = t * 8;
            *(u16x8*)&SM[L]         = sreg[0];
            *(u16x8*)&SM[L + 2048]  = sreg[1];
            *(u16x8*)&SM[L + 4096]  = sreg[2];
            *(u16x8*)&SM[L + 6144]  = sreg[3];
            *(u16x8*)&SM[L + 8192]  = sreg[4];
            *(u16x8*)&SM[L + 10240] = sreg[5];
            *(u16x8*)&SM[L + 12288] = sreg[6];
            *(u16x8*)&SM[L + 14336] = sreg[7];
        }
        __syncthreads();                       // staging visible

        // issue next step's staging loads (consumed at next barrier;
        // final iteration overreads into the adjacent plane, never consumed)
        stage_load();

        bf16x8 cah[4], cal[4], cbh[4], cbl[4];
#pragma unroll
        for (int i = 0; i < 4; i++) {
            cah[i] = *(const bf16x8*)&SM[aoff + i * 512 + lp];
            cal[i] = *(const bf16x8*)&SM[4096 + aoff + i * 512 + lp];
        }
#pragma unroll
        for (int j = 0; j < 4; j++) {
            cbh[j] = *(const bf16x8*)&SM[boff + j * 512 + lp];
            cbl[j] = *(const bf16x8*)&SM[4096 + boff + j * 512 + lp];
        }

        __builtin_amdgcn_s_setprio(1);
#pragma unroll
        for (int j = 0; j < 4; j++)
#pragma unroll
            for (int i = 0; i < 4; i++) {
                acc[i][j] = __builtin_amdgcn_mfma_f32_16x16x32_bf16(cah[i], cbh[j], acc[i][j], 0, 0, 0);
                acc[i][j] = __builtin_amdgcn_mfma_f32_16x16x32_bf16(cal[i], cbh[j], acc[i][j], 0, 0, 0);
                acc[i][j] = __builtin_amdgcn_mfma_f32_16x16x32_bf16(cah[i], cbl[j], acc[i][j], 0, 0, 0);
            }
        __builtin_amdgcn_s_setprio(0);
    }

    // ---- epilogue ----
    const int b      = m0 >> 11;
    const int head   = (n0 >> 6) + (w >> 1);
    const int m_base = m0 + am;

    if (proj < 2) {
#pragma unroll
        for (int i = 0; i < 4; i++) {
#pragma unroll
            for (int r = 0; r < 4; r++) {
                const int s = (m_base + i * 16 + quad * 4 + r) & 2047;
                const float* ctr = ct + s * HDIM;
                const float* str = st + s * HDIM;
                float nv[4];
#pragma unroll
                for (int j = 0; j < 4; j++) {
                    const int dh = j * 16 + lx;
                    const float c  = ctr[dh];
                    const float sn = str[dh];
                    const float x  = acc[i][j][r];
                    const float p  = acc[i][j ^ 2][r];
                    nv[j] = (j < 2) ? (x * c - p * sn) : (x * c + p * sn);
                }
#pragma unroll
                for (int j = 0; j < 4; j++) acc[i][j][r] = nv[j];
            }
        }
        u16* dh_ = (proj == 0) ? Qhi : Khi;
        u16* dl_ = (proj == 0) ? Qlo : Klo;
        const float qscale = (proj == 0) ? 0.18033688011112042f : 1.0f;
        const size_t obase = (size_t)(b * NHEADS + head) * SEQ * HDIM;
#pragma unroll
        for (int i = 0; i < 4; i++)
#pragma unroll
            for (int r = 0; r < 4; r++) {
                const int s   = (m_base + i * 16 + quad * 4 + r) & 2047;
                const int rb  = s >> 4;
                const int lxq = s & 15;
#pragma unroll
                for (int j = 0; j < 4; j++) {
                    const size_t fo = obase + ((size_t)rb * 2 + (j >> 1)) * 512
                                    + (size_t)((j & 1) * 2 + (lx >> 3)) * 128
                                    + (size_t)lxq * 8 + (lx & 7);
                    u16 hh, ll;
                    split1(acc[i][j][r] * qscale, hh, ll);
                    dh_[fo] = hh;
                    dl_[fo] = ll;
                }
            }
    } else {
#pragma unroll 1
        for (int pass = 0; pass < 2; pass++) {
            __syncthreads();
            if ((w & 1) == pass) {
#pragma unroll
                for (int i = 0; i < 4; i++)
#pragma unroll
                    for (int j = 0; j < 4; j++)
#pragma unroll
                        for (int r = 0; r < 4; r++) {
                            const int ml = i * 16 + quad * 4 + r;
                            const int nl = bn + j * 16 + lx;
                            const float v = acc[i][j][r];
                            unsigned u  = __float_as_uint(v);
                            unsigned hi = u & 0xFFFF0000u;
                            unsigned lo = __float_as_uint(v - __uint_as_float(hi)) >> 16;
                            vtr[ml][nl] = hi | lo;
                        }
            }
            __syncthreads();
            {
                const int d      = t >> 1;            // 0..127 (2 heads x 64)
                const int sh     = (t & 1) * 32;
                const int headv  = (n0 >> 6) + (d >> 6);
                const int dd     = d & 63;
                const size_t vbase = (size_t)(b * NHEADS + headv) * SEQ * HDIM;
                const int s0base = (m0 & 2047) + pass * 64 + sh;
#pragma unroll
                for (int k = 0; k < 4; k++) {
                    const int s0 = s0base + k * 8;
                    u16x8 hv, lv;
#pragma unroll
                    for (int e = 0; e < 8; e++) {
                        unsigned u = vtr[sh + k * 8 + e][d];
                        hv[e] = (u16)(u >> 16);
                        lv[e] = (u16)(u & 0xFFFFu);
                    }
                    const size_t fo = vbase + ((size_t)(dd >> 4) * 64 + (s0 >> 5)) * 512
                                    + (size_t)((s0 >> 3) & 3) * 128 + (size_t)(dd & 15) * 8;
                    *(u16x8*)(Vhi + fo) = hv;
                    *(u16x8*)(Vlo + fo) = lv;
                }
            }
        }
    }
}

// ---------------------------------------------------------------------------
// Flash attention (byte-identical to round 12, verified 128 us): LDS-staged
// K/V (6 chunks/thread, linear pointers), Vlo direct-global, PS round-trip,
// linear Vlo fragment pointers, setprio, launch_bounds (256,2).
// ---------------------------------------------------------------------------
__global__ __launch_bounds__(256, 2) void attn_kernel(
    const u16* __restrict__ Qhi, const u16* __restrict__ Qlo,
    const u16* __restrict__ Khi, const u16* __restrict__ Klo,
    const u16* __restrict__ Vhi, const u16* __restrict__ Vlo,
    float* __restrict__ OUT)
{
    __shared__ __align__(16) u16 KVs[3][4096];   // Khi, Klo, Vhi tiles (24 KB)
    __shared__ float PS[4][32][68];              // 34816 B

    const int t    = threadIdx.x;
    const int lane = t & 63;
    const int w    = t >> 6;
    const int lx   = lane & 15;
    const int quad = lane >> 4;

    const int q0 = blockIdx.x * 128;
    const int h  = blockIdx.y;
    const int b  = blockIdx.z;
    const size_t base = (size_t)(b * NHEADS + h) * SEQ * HDIM;
    const int lp = quad * 128 + lx * 8;

    // Q fragments (already split + pre-scaled in workspace)
    bf16x8 qh[2][2], ql[2][2];
#pragma unroll
    for (int a = 0; a < 2; a++)
#pragma unroll
        for (int ks = 0; ks < 2; ks++) {
            const size_t fo = base + ((size_t)((q0 >> 4) + w * 2 + a) * 2 + ks) * 512 + lp;
            qh[a][ks] = *(const bf16x8*)(Qhi + fo);
            ql[a][ks] = *(const bf16x8*)(Qlo + fo);
        }

    f32x4 O[2][4];
    float l_part[2][4];
#pragma unroll
    for (int a = 0; a < 2; a++) {
#pragma unroll
        for (int dt = 0; dt < 4; dt++) O[a][dt] = (f32x4){0.f,0.f,0.f,0.f};
#pragma unroll
        for (int r = 0; r < 4; r++) l_part[a][r] = 0.f;
    }

    // --- staging machinery: 6 chunks/thread (2 halves x 3 planes), linear
    // pointers with constant strides ---
    const int o0 = t * 8;            // [0,2048)
    const int o1 = o0 + 2048;        // [2048,4096)
    const u16* pKh0 = Khi + base + o0;
    const u16* pKh1 = Khi + base + o1;
    const u16* pKl0 = Klo + base + o0;
    const u16* pKl1 = Klo + base + o1;
    const u16* pVh0 = Vhi + base + ((size_t)(o0 >> 10) * 64) * 512 + (o0 & 1023);
    const u16* pVh1 = Vhi + base + ((size_t)(o1 >> 10) * 64) * 512 + (o1 & 1023);
    u16x8 sreg[6];
    auto stage_load = [&]() {
        sreg[0] = *(const u16x8*)pKh0;  pKh0 += 4096;   // K tile stride
        sreg[1] = *(const u16x8*)pKh1;  pKh1 += 4096;
        sreg[2] = *(const u16x8*)pKl0;  pKl0 += 4096;
        sreg[3] = *(const u16x8*)pKl1;  pKl1 += 4096;
        sreg[4] = *(const u16x8*)pVh0;  pVh0 += 1024;   // V tile stride
        sreg[5] = *(const u16x8*)pVh1;  pVh1 += 1024;
    };

    // --- Vlo fragment pointers: 8 linear pointers, +1024/tile ---
    const u16* pVl[2][4];
#pragma unroll
    for (int dt = 0; dt < 4; dt++)
#pragma unroll
        for (int ks2 = 0; ks2 < 2; ks2++)
            pVl[ks2][dt] = Vlo + base + ((size_t)dt * 64 + ks2) * 512 + lp;

    stage_load();

#pragma unroll 1
    for (int kt = 0; kt < SEQ; kt += 64) {
        __syncthreads();                       // prev body done reading KVs
        {
            *(u16x8*)&KVs[0][o0] = sreg[0];
            *(u16x8*)&KVs[0][o1] = sreg[1];
            *(u16x8*)&KVs[1][o0] = sreg[2];
            *(u16x8*)&KVs[1][o1] = sreg[3];
            *(u16x8*)&KVs[2][o0] = sreg[4];
            *(u16x8*)&KVs[2][o1] = sreg[5];
        }
        __syncthreads();                       // staging visible

        // issue next tile's staging loads (consumed at next barrier;
        // final iteration overreads into the adjacent plane, never consumed)
        stage_load();

        // ---- Vlo fragments: direct global (early issue, consumed in PV) ----
        bf16x8 vl[2][4];
#pragma unroll
        for (int dt = 0; dt < 4; dt++)
#pragma unroll
            for (int ks2 = 0; ks2 < 2; ks2++) {
                vl[ks2][dt] = *(const bf16x8*)pVl[ks2][dt];
                pVl[ks2][dt] += 1024;
            }

        // ---- K fragments from LDS ----
        bf16x8 kh[2][4], kl[2][4];
#pragma unroll
        for (int c = 0; c < 4; c++)
#pragma unroll
            for (int ks = 0; ks < 2; ks++) {
                kh[ks][c] = *(const bf16x8*)&KVs[0][(c * 2 + ks) * 512 + lp];
                kl[ks][c] = *(const bf16x8*)&KVs[1][(c * 2 + ks) * 512 + lp];
            }

        // ---- scores + exp -> PS ----
#pragma unroll
        for (int a = 0; a < 2; a++) {
#pragma unroll
            for (int c = 0; c < 4; c++) {
                f32x4 acc = (f32x4){0.f,0.f,0.f,0.f};
                __builtin_amdgcn_s_setprio(1);
#pragma unroll
                for (int ks = 0; ks < 2; ks++) {
                    acc = __builtin_amdgcn_mfma_f32_16x16x32_bf16(qh[a][ks], kh[ks][c], acc, 0, 0, 0);
                    acc = __builtin_amdgcn_mfma_f32_16x16x32_bf16(ql[a][ks], kh[ks][c], acc, 0, 0, 0);
                    acc = __builtin_amdgcn_mfma_f32_16x16x32_bf16(qh[a][ks], kl[ks][c], acc, 0, 0, 0);
                }
                __builtin_amdgcn_s_setprio(0);
#pragma unroll
                for (int r = 0; r < 4; r++) {
                    float p = exp2f(acc[r]);           // Q pre-scaled: 2^(qk*log2e/8)
                    l_part[a][r] += p;
                    PS[w][a * 16 + quad * 4 + r][c * 16 + lx] = p;
                }
            }
        }

        // ---- Vhi fragments from LDS ----
        bf16x8 vh[2][4];
#pragma unroll
        for (int dt = 0; dt < 4; dt++)
#pragma unroll
            for (int ks2 = 0; ks2 < 2; ks2++)
                vh[ks2][dt] = *(const bf16x8*)&KVs[2][dt * 1024 + ks2 * 512 + lp];

        // ---- PV ----
#pragma unroll
        for (int a = 0; a < 2; a++) {
#pragma unroll
            for (int ks2 = 0; ks2 < 2; ks2++) {
                const float* ps = &PS[w][a * 16 + lx][ks2 * 32 + quad * 8];
                float pf[8];
                *(float4*)&pf[0] = *(const float4*)ps;
                *(float4*)&pf[4] = *(const float4*)(ps + 4);
                bf16x8 phi, plo;
                split8(pf, phi, plo);
                __builtin_amdgcn_s_setprio(1);
#pragma unroll
                for (int dt = 0; dt < 4; dt++) {
                    O[a][dt] = __builtin_amdgcn_mfma_f32_16x16x32_bf16(phi, vh[ks2][dt], O[a][dt], 0, 0, 0);
                    O[a][dt] = __builtin_amdgcn_mfma_f32_16x16x32_bf16(plo, vh[ks2][dt], O[a][dt], 0, 0, 0);
                    O[a][dt] = __builtin_amdgcn_mfma_f32_16x16x32_bf16(phi, vl[ks2][dt], O[a][dt], 0, 0, 0);
                }
                __builtin_amdgcn_s_setprio(0);
            }
        }
    }

    float linv[2][4];
#pragma unroll
    for (int a = 0; a < 2; a++)
#pragma unroll
        for (int r = 0; r < 4; r++) {
            float l = l_part[a][r];
            l += __shfl_xor(l, 1);
            l += __shfl_xor(l, 2);
            l += __shfl_xor(l, 4);
            l += __shfl_xor(l, 8);
            linv[a][r] = 1.f / l;
        }

    float* Po = &PS[0][0][0];   // reuse as [128][68]
    __syncthreads();            // all waves done with their PS regions
#pragma unroll
    for (int a = 0; a < 2; a++)
#pragma unroll
        for (int dt = 0; dt < 4; dt++)
#pragma unroll
            for (int r = 0; r < 4; r++)
                Po[(size_t)(w * 32 + a * 16 + quad * 4 + r) * 68 + dt * 16 + lx] =
                    O[a][dt][r] * linv[a][r];
    __syncthreads();
    {
        const int q    = t >> 1;
        const int half = t & 1;
        const float* prow = Po + (size_t)q * 68 + half * 32;
        float* dst = OUT + ((size_t)(b * SEQ + q0 + q)) * HID + h * HDIM + half * 32;
#pragma unroll
        for (int e = 0; e < 8; e++)
            ((float4*)dst)[e] = ((const float4*)prow)[e];
    }
}

// ---------------------------------------------------------------------------
extern "C" void kernel_launch(void* const* d_in, const int* in_sizes, int n_in,
                              void* d_out, int out_size, void* d_ws, size_t ws_size,
                              hipStream_t stream)
{
    const float* X  = (const float*)d_in[0];
    const float* Wq = (const float*)d_in[1];
    const float* Wk = (const float*)d_in[2];
    const float* Wv = (const float*)d_in[3];
    float* out = (float*)d_out;

    const size_t qkv_elems = (size_t)BATCH * NHEADS * SEQ * HDIM;  // 4,194,304
    char* wsb = (char*)d_ws;
    float* ct  = (float*)wsb;                       // 0.5 MB
    float* st  = ct + (size_t)SEQ * HDIM;           // 0.5 MB
    u16* Xhi = (u16*)(st + (size_t)SEQ * HDIM);     // 8 MB
    u16* Xlo = Xhi + (size_t)NX;                    // 8 MB
    u16* Whi = Xlo + (size_t)NX;                    // 6 MB
    u16* Wlo = Whi + 3 * (size_t)NW;                // 6 MB
    u16* Qhi = Wlo + 3 * (size_t)NW;                // 8 MB
    u16* Qlo = Qhi + qkv_elems;                     // 8 MB
    u16* Khi = Qlo + qkv_elems;                     // 8 MB
    u16* Klo = Khi + qkv_elems;                     // 8 MB
    u16* Vhi = Klo + qkv_elems;                     // 8 MB
    u16* Vlo = Vhi + qkv_elems;                     // 8 MB   (total 77 MB)

    rope_tables_kernel<<<(SEQ * HDIM + 255) / 256, 256, 0, stream>>>(ct, st);

    // 14336 subtiles (8192 X + 3*2048 W), 4 per 256-thread block
    split_kernel<<<3584, 256, 0, stream>>>(
        X, Wq, Wk, Wv, Xhi, Xlo, Whi, Wlo);

    qkv_mfma_kernel<<<dim3(3 * (HID / 128) * ((BATCH * SEQ) / 128)), 256, 0, stream>>>(
        Xhi, Xlo, Whi, Wlo, ct, st, Qhi, Qlo, Khi, Klo, Vhi, Vlo);

    attn_kernel<<<dim3(SEQ / 128, NHEADS, BATCH), 256, 0, stream>>>(
        Qhi, Qlo, Khi, Klo, Vhi, Vlo, out);
}